// Round 2
// baseline (3851.017 us; speedup 1.0000x reference)
//
#include <hip/hip_runtime.h>
#include <math.h>

#define Bsz 1024
#define Npt 50
#define Hd 128
#define G4 512
#define Tt 50
#define NEGC 1000000000.0f
#define CTANH 10.0f

#define OFF_R 0
#define OFF_V 1024
#define OFF_LP 2048
#define OFF_A 2562048
#define OFF_C 2613248
#define OFF_P 2715648

// workspace float offsets
#define WS_TG 0        // 128 float4: {Mg0, Mg1, vg, cg}
#define WS_TP 512      // 128 float4: {Mp0, Mp1, vp, cp}
#define WS_TQ 1024     // 128 float4: {Pg0, Pg1, pc'=cg@Wqp+cp, 0}
#define WS_TW 1536     // 128 float4: {We0, We1, bemb, 0}
#define WS_WQT 2048    // 16384 floats: Wqg transposed [hh][k]

__device__ __forceinline__ float fsig(float x) {
  return 1.0f / (1.0f + __expf(-x));
}

__device__ __forceinline__ float ftanh(float x) {
  float x2 = x * x;
  float p = x * (1.0f + x2 * (-0.33333333f + x2 * 0.13333333f));
  float e = __expf(2.0f * x);
  float tv = 1.0f - 2.0f * __builtin_amdgcn_rcpf(e + 1.0f);
  return (fabsf(x) < 0.1f) ? p : tv;
}

// full-wave64 sum via DPP (VALU pipe, not LDS); result valid in lane 63
__device__ __forceinline__ float dpp_sum64(float x) {
  int v;
  v = __builtin_amdgcn_update_dpp(0, __float_as_int(x), 0x111, 0xf, 0xf, true);
  x += __int_as_float(v);
  v = __builtin_amdgcn_update_dpp(0, __float_as_int(x), 0x112, 0xf, 0xf, true);
  x += __int_as_float(v);
  v = __builtin_amdgcn_update_dpp(0, __float_as_int(x), 0x114, 0xf, 0xf, true);
  x += __int_as_float(v);
  v = __builtin_amdgcn_update_dpp(0, __float_as_int(x), 0x118, 0xf, 0xf, true);
  x += __int_as_float(v);
  v = __builtin_amdgcn_update_dpp(0, __float_as_int(x), 0x142, 0xf, 0xf, true);
  x += __int_as_float(v);
  v = __builtin_amdgcn_update_dpp(0, __float_as_int(x), 0x143, 0xf, 0xf, true);
  x += __int_as_float(v);
  return x;
}

__device__ __forceinline__ float xsum(float x) {
  #pragma unroll
  for (int off = 32; off >= 1; off >>= 1) x += __shfl_xor(x, off, 64);
  return x;
}
__device__ __forceinline__ float xmax(float x) {
  #pragma unroll
  for (int off = 32; off >= 1; off >>= 1) x = fmaxf(x, __shfl_xor(x, off, 64));
  return x;
}

// Precompute rank-2 tables and Wqg^T into ws.
__global__ __launch_bounds__(256) void k_pre(const float* __restrict__ Wemb,
                                             const float* __restrict__ bemb,
                                             const float* __restrict__ Wqg,
                                             const float* __restrict__ Wrg,
                                             const float* __restrict__ vg,
                                             const float* __restrict__ Wqp,
                                             const float* __restrict__ Wrp,
                                             const float* __restrict__ vp,
                                             float* __restrict__ ws) {
  __shared__ float mg_s[2][128], mp_s[2][128], cg_s[128], cp_s[128];
  __shared__ float pg_s[2][128], pc_s[128];
  int t = threadIdx.x, blk = blockIdx.x;
  if (blk > 0) {
    int f = (blk - 1) * 256 + t;   // 64 blocks x 256 = 16384
    ws[WS_WQT + f] = Wqg[(f & 127) * Hd + (f >> 7)];
    return;
  }
  int j = t >> 7, hh = t & 127;
  float ag = 0.f, ap = 0.f;
  for (int k = 0; k < 128; ++k) {
    float we = Wemb[j * 128 + k];
    ag = fmaf(we, Wrg[k * 128 + hh], ag);
    ap = fmaf(we, Wrp[k * 128 + hh], ap);
  }
  mg_s[j][hh] = ag; mp_s[j][hh] = ap;
  if (t < 128) {
    float cgv = 0.f, cpv = 0.f;
    for (int k = 0; k < 128; ++k) {
      float be = bemb[k];
      cgv = fmaf(be, Wrg[k * 128 + t], cgv);
      cpv = fmaf(be, Wrp[k * 128 + t], cpv);
    }
    cg_s[t] = cgv; cp_s[t] = cpv;
  }
  __syncthreads();
  float pg = 0.f;
  for (int k = 0; k < 128; ++k) pg = fmaf(mg_s[j][k], Wqp[k * 128 + hh], pg);
  pg_s[j][hh] = pg;
  if (t < 128) {
    float pcv = 0.f;
    for (int k = 0; k < 128; ++k) pcv = fmaf(cg_s[k], Wqp[k * 128 + t], pcv);
    pc_s[t] = pcv + cp_s[t];
  }
  __syncthreads();
  if (t < 128) {
    float4* w4 = (float4*)ws;
    w4[WS_TG / 4 + t] = make_float4(mg_s[0][t], mg_s[1][t], vg[t], cg_s[t]);
    w4[WS_TP / 4 + t] = make_float4(mp_s[0][t], mp_s[1][t], vp[t], cp_s[t]);
    w4[WS_TQ / 4 + t] = make_float4(pg_s[0][t], pg_s[1][t], pc_s[t], 0.f);
    w4[WS_TW / 4 + t] = make_float4(Wemb[t], Wemb[128 + t], bemb[t], 0.f);
  }
}

// Persistent kernel: 256 blocks x 1024 threads, 4 batch rows per block,
// full T=50 scan + epilogue inside. No cross-block dependencies.
__global__ __launch_bounds__(1024) void k_mega(const float* __restrict__ ip,
                                               const float* __restrict__ dinit,
                                               const float* __restrict__ Wi,
                                               const float* __restrict__ Wh,
                                               const float* __restrict__ bl,
                                               const float* __restrict__ Wrc,
                                               const float* __restrict__ W1,
                                               const float* __restrict__ b1,
                                               const float* __restrict__ W2,
                                               const float* __restrict__ b2,
                                               const float* __restrict__ ws,
                                               float* __restrict__ out) {
  __shared__ __align__(16) float gpart[8][4][G4];     // 64 KB gates partials
  __shared__ __align__(16) float h_s[4][Hd];
  __shared__ __align__(16) float c_s[4][Hd];
  __shared__ __align__(16) float dec_s[4][Hd];
  __shared__ __align__(16) float qbuf[4][Hd];
  __shared__ __align__(16) float u_s[4][64];
  __shared__ __align__(16) float ip_s[4][Npt * 2];
  __shared__ __align__(16) float mask_s[4][Npt];
  __shared__ __align__(16) float ch_s[4][Npt * 2];

  int t = threadIdx.x, blk = blockIdx.x;
  int w = t >> 6, lane = t & 63;

  // ---- prologue: stage per-block state ----
  if (t < 200) ((float2*)ip_s)[t] = ((const float2*)ip)[blk * 200 + t];
  if (t < 512) {
    int r = t >> 7, hh = t & 127;
    h_s[r][hh] = 0.f;
    c_s[r][hh] = 0.f;
    dec_s[r][hh] = dinit[hh];
  }
  if (t < 200) ((float*)mask_s)[t] = 0.f;
  __syncthreads();

  int cr = w & 3, ni = w >> 2;            // score-phase wave mapping
  int nIter = (ni == 3) ? 11 : 13;
  float2 ipw[13];
  #pragma unroll
  for (int i = 0; i < 13; ++i) {
    int n = ni * 13 + i;
    ipw[i] = (n < Npt) ? ((float2*)ip_s)[cr * Npt + n] : make_float2(0.f, 0.f);
  }
  const float4* ws4 = (const float4*)ws;
  const float* wqt = ws + WS_WQT;

  for (int st = 0; st < Tt; ++st) {
    // ---- A1: gates partials: 8 k-chunks x 128 j-tiles(4 cols) x 4 rows ----
    {
      int kh = t >> 7, jt = t & 127;
      int k0 = kh * 16;
      float acc[4][4];
      #pragma unroll
      for (int r = 0; r < 4; ++r)
        #pragma unroll
        for (int c = 0; c < 4; ++c) acc[r][c] = 0.f;
      #pragma unroll
      for (int k4 = 0; k4 < 16; k4 += 4) {
        float xr[4][4], hr[4][4];
        #pragma unroll
        for (int r = 0; r < 4; ++r) {
          *(float4*)&xr[r][0] = *(const float4*)&dec_s[r][k0 + k4];
          *(float4*)&hr[r][0] = *(const float4*)&h_s[r][k0 + k4];
        }
        #pragma unroll
        for (int kk = 0; kk < 4; ++kk) {
          float wi4[4], wh4[4];
          *(float4*)wi4 = *(const float4*)&Wi[(k0 + k4 + kk) * G4 + jt * 4];
          *(float4*)wh4 = *(const float4*)&Wh[(k0 + k4 + kk) * G4 + jt * 4];
          #pragma unroll
          for (int r = 0; r < 4; ++r)
            #pragma unroll
            for (int c = 0; c < 4; ++c)
              acc[r][c] = fmaf(xr[r][kk], wi4[c], fmaf(hr[r][kk], wh4[c], acc[r][c]));
        }
      }
      #pragma unroll
      for (int r = 0; r < 4; ++r)
        *(float4*)&gpart[kh][r][jt * 4] = *(float4*)&acc[r][0];
    }
    __syncthreads();
    // ---- A2: combine partials + bias + LSTM cell ----
    if (t < 512) {
      int r = t >> 7, hh = t & 127;
      float gi = bl[hh], gf = bl[128 + hh], gg = bl[256 + hh], go = bl[384 + hh];
      #pragma unroll
      for (int kh = 0; kh < 8; ++kh) {
        gi += gpart[kh][r][hh];
        gf += gpart[kh][r][128 + hh];
        gg += gpart[kh][r][256 + hh];
        go += gpart[kh][r][384 + hh];
      }
      float c2 = fsig(gf) * c_s[r][hh] + fsig(gi) * ftanh(gg);
      float h2 = fsig(go) * ftanh(c2);
      c_s[r][hh] = c2;
      h_s[r][hh] = h2;
    }
    __syncthreads();
    // ---- B: q = h2 @ Wqg (+cg folded) ----
    if (t < 512) {
      int r = t >> 7, hh = t & 127;
      float a = 0.f;
      const float* wrow = wqt + hh * 128;
      #pragma unroll
      for (int k = 0; k < 128; k += 4) {
        float wv[4], hv[4];
        *(float4*)wv = *(const float4*)&wrow[k];
        *(float4*)hv = *(const float4*)&h_s[r][k];
        a = fmaf(hv[0], wv[0], fmaf(hv[1], wv[1], fmaf(hv[2], wv[2], fmaf(hv[3], wv[3], a))));
      }
      qbuf[r][hh] = a + ws4[WS_TG / 4 + hh].w;   // + cg
    }
    __syncthreads();
    // ---- C: glimpse scores u[n] = sum_h vg[h]*tanh(eg(n,h)+q[h]) ----
    {
      float4 tA = ws4[WS_TG / 4 + lane];
      float4 tB = ws4[WS_TG / 4 + 64 + lane];
      float q0 = qbuf[cr][lane], q1 = qbuf[cr][64 + lane];
      #pragma unroll 2
      for (int i = 0; i < nIter; ++i) {
        int n = ni * 13 + i;
        float p0 = ipw[i].x, p1 = ipw[i].y;
        float a0 = fmaf(p0, tA.x, fmaf(p1, tA.y, q0));
        float a1 = fmaf(p0, tB.x, fmaf(p1, tB.y, q1));
        float s = tA.z * ftanh(a0) + tB.z * ftanh(a1);
        s = dpp_sum64(s);
        if (lane == 63) u_s[cr][n] = s;
      }
    }
    __syncthreads();
    // ---- D: glimpse softmax -> (s0,s1) -> qbuf = gp + cp (rank-2) ----
    if (w < 4) {
      int r = w;
      float2 ipn = make_float2(0.f, 0.f);
      float x = -INFINITY;
      if (lane < Npt) {
        ipn = ((float2*)ip_s)[r * Npt + lane];
        x = u_s[r][lane] - NEGC * mask_s[r][lane];
      }
      float m = xmax(x);
      float e = (lane < Npt) ? __expf(x - m) : 0.f;
      float ssum = xsum(e);
      float p = e / ssum;
      float s0 = xsum(p * ipn.x);
      float s1 = xsum(p * ipn.y);
      float4 tq0 = ws4[WS_TQ / 4 + lane];
      float4 tq1 = ws4[WS_TQ / 4 + 64 + lane];
      qbuf[r][lane]      = fmaf(s0, tq0.x, fmaf(s1, tq0.y, tq0.z));
      qbuf[r][64 + lane] = fmaf(s0, tq1.x, fmaf(s1, tq1.y, tq1.z));
    }
    __syncthreads();
    // ---- E: pointer scores -> logit = 10*tanh(u2) (mask applied in F) ----
    {
      float4 tA = ws4[WS_TP / 4 + lane];
      float4 tB = ws4[WS_TP / 4 + 64 + lane];
      float q0 = qbuf[cr][lane], q1 = qbuf[cr][64 + lane];
      #pragma unroll 2
      for (int i = 0; i < nIter; ++i) {
        int n = ni * 13 + i;
        float p0 = ipw[i].x, p1 = ipw[i].y;
        float a0 = fmaf(p0, tA.x, fmaf(p1, tA.y, q0));
        float a1 = fmaf(p0, tB.x, fmaf(p1, tB.y, q1));
        float s = tA.z * ftanh(a0) + tB.z * ftanh(a1);
        s = dpp_sum64(s);
        if (lane == 63) u_s[cr][n] = CTANH * ftanh(s);
      }
    }
    __syncthreads();
    // ---- F: pointer softmax / argmax / outputs / mask / dec_next ----
    if (w < 4) {
      int r = w, b = blk * 4 + r;
      float2 ipn = make_float2(0.f, 0.f);
      float x = -INFINITY;
      if (lane < Npt) {
        ipn = ((float2*)ip_s)[r * Npt + lane];
        x = u_s[r][lane] - NEGC * mask_s[r][lane];
      }
      float m = xmax(x);
      float sh = x - m;
      float e = (lane < Npt) ? __expf(sh) : 0.f;
      float ssum = xsum(e);
      float ls = __logf(ssum);
      float prob = e / ssum;
      if (lane < Npt) {
        out[OFF_LP + ((size_t)b * Tt + st) * Npt + lane] = sh - ls;
        out[OFF_P + ((size_t)b * Tt + st) * Npt + lane] = prob;
      }
      float pv = (lane < Npt) ? prob : -1.f;
      int idx = lane;
      #pragma unroll
      for (int off = 32; off >= 1; off >>= 1) {
        float po = __shfl_xor(pv, off, 64);
        int io = __shfl_xor(idx, off, 64);
        if (po > pv || (po == pv && io < idx)) { pv = po; idx = io; }
      }
      int a = idx;
      float p0a = __shfl(ipn.x, a, 64);
      float p1a = __shfl(ipn.y, a, 64);
      if (lane == 0) {
        out[OFF_A + (size_t)b * Tt + st] = (float)a;
        out[OFF_C + ((size_t)b * Tt + st) * 2 + 0] = p0a;
        out[OFF_C + ((size_t)b * Tt + st) * 2 + 1] = p1a;
        ((float2*)ch_s)[r * Npt + st] = make_float2(p0a, p1a);
        mask_s[r][a] = 1.0f;
      }
      float4 tw0 = ws4[WS_TW / 4 + lane];
      float4 tw1 = ws4[WS_TW / 4 + 64 + lane];
      dec_s[r][lane]      = fmaf(p0a, tw0.x, fmaf(p1a, tw0.y, tw0.z));
      dec_s[r][64 + lane] = fmaf(p0a, tw1.x, fmaf(p1a, tw1.y, tw1.z));
    }
    __syncthreads();
  }

  // ---- epilogue: critic (hy = dec_last@Wrc; v = relu(hy@W1+b1)@W2+b2), R ----
  float* scr = &gpart[0][0][0];
  if (t < 512) {
    int r = t >> 7, hh = t & 127;
    float a = 0.f;
    #pragma unroll 4
    for (int k = 0; k < 128; ++k) a = fmaf(dec_s[r][k], Wrc[k * 128 + hh], a);
    qbuf[r][hh] = a;
  }
  __syncthreads();
  if (t < 512) {
    int r = t >> 7, hh = t & 127;
    float a = b1[hh];
    #pragma unroll 4
    for (int k = 0; k < 128; ++k) a = fmaf(qbuf[r][k], W1[k * 128 + hh], a);
    scr[r * 128 + hh] = fmaxf(a, 0.f);
  }
  __syncthreads();
  if (w < 4) {
    int r = w, b = blk * 4 + r;
    float sv = scr[r * 128 + lane] * W2[lane] + scr[r * 128 + 64 + lane] * W2[64 + lane];
    sv = xsum(sv);
    if (lane == 0) out[OFF_V + b] = sv + b2[0];
    float rr = 0.f;
    if (lane < Npt) {
      float2 c0 = ((float2*)ch_s)[r * Npt + lane];
      float2 c1 = ((float2*)ch_s)[r * Npt + ((lane == Npt - 1) ? 0 : lane + 1)];
      float dx = c1.x - c0.x, dy = c1.y - c0.y;
      rr = sqrtf(dx * dx + dy * dy + 1e-10f);
    }
    rr = xsum(rr);
    if (lane == 0) out[OFF_R + b] = rr;
  }
}

extern "C" void kernel_launch(void* const* d_in, const int* in_sizes, int n_in,
                              void* d_out, int out_size, void* d_ws, size_t ws_size,
                              hipStream_t stream) {
  (void)in_sizes; (void)n_in; (void)out_size; (void)ws_size;
  const float* ip    = (const float*)d_in[0];
  const float* Wemb  = (const float*)d_in[1];
  const float* bemb  = (const float*)d_in[2];
  const float* dinit = (const float*)d_in[3];
  const float* Wi    = (const float*)d_in[4];
  const float* Wh    = (const float*)d_in[5];
  const float* bl    = (const float*)d_in[6];
  const float* Wqg   = (const float*)d_in[7];
  const float* Wrg   = (const float*)d_in[8];
  const float* vg    = (const float*)d_in[9];
  const float* Wqp   = (const float*)d_in[10];
  const float* Wrp   = (const float*)d_in[11];
  const float* vp    = (const float*)d_in[12];
  // d_in[13..16], d_in[18] dead: critic N=1 softmax == 1 => hy = e_c
  const float* Wrc   = (const float*)d_in[17];
  const float* W1    = (const float*)d_in[19];
  const float* b1    = (const float*)d_in[20];
  const float* W2    = (const float*)d_in[21];
  const float* b2    = (const float*)d_in[22];
  float* out = (float*)d_out;
  float* ws  = (float*)d_ws;

  k_pre<<<65, 256, 0, stream>>>(Wemb, bemb, Wqg, Wrg, vg, Wqp, Wrp, vp, ws);
  k_mega<<<256, 1024, 0, stream>>>(ip, dinit, Wi, Wh, bl, Wrc, W1, b1, W2, b2, ws, out);
}

// Round 3
// 1452.300 us; speedup vs baseline: 2.6517x; 2.6517x over previous
//
#include <hip/hip_runtime.h>
#include <math.h>

#define Bsz 1024
#define Npt 50
#define Hd 128
#define G4 512
#define Tt 50
#define NEGC 1000000000.0f
#define CTANH 10.0f
#define BN (Bsz*Npt)
#define BH (Bsz*Hd)

#define OFF_R 0
#define OFF_V 1024
#define OFF_LP 2048
#define OFF_A 2562048
#define OFF_C 2613248
#define OFF_P 2715648

// workspace float offsets
#define WS_TG 0        // 128 float4: {Mg0, Mg1, vg, cg}
#define WS_TP 512      // 128 float4: {Mp0, Mp1, vp, cp}
#define WS_TQ 1024     // 128 float4: {Pg0, Pg1, cg@Wqp+cp, 0}
#define WS_TW 1536     // 128 float4: {We0, We1, bemb, 0}
#define WS_WQT 2048    // 16384: Wqg^T [hh][k]
#define WS_H    18432
#define WS_C    (WS_H + BH)
#define WS_DEC  (WS_C + BH)
#define WS_MASK (WS_DEC + BH)
#define WS_EC   (WS_MASK + BN)
#define WS_T2   (WS_EC + BH)

__device__ __forceinline__ float fsig(float x) {
  return 1.0f / (1.0f + __expf(-x));
}

__device__ __forceinline__ float ftanh(float x) {
  float x2 = x * x;
  float p = x * (1.0f + x2 * (-0.33333333f + x2 * 0.13333333f));
  float e = __expf(2.0f * x);
  float tv = 1.0f - 2.0f * __builtin_amdgcn_rcpf(e + 1.0f);
  return (fabsf(x) < 0.1f) ? p : tv;
}

__device__ __forceinline__ float dpp_sum64(float x) {
  int v;
  v = __builtin_amdgcn_update_dpp(0, __float_as_int(x), 0x111, 0xf, 0xf, true);
  x += __int_as_float(v);
  v = __builtin_amdgcn_update_dpp(0, __float_as_int(x), 0x112, 0xf, 0xf, true);
  x += __int_as_float(v);
  v = __builtin_amdgcn_update_dpp(0, __float_as_int(x), 0x114, 0xf, 0xf, true);
  x += __int_as_float(v);
  v = __builtin_amdgcn_update_dpp(0, __float_as_int(x), 0x118, 0xf, 0xf, true);
  x += __int_as_float(v);
  v = __builtin_amdgcn_update_dpp(0, __float_as_int(x), 0x142, 0xf, 0xf, true);
  x += __int_as_float(v);
  v = __builtin_amdgcn_update_dpp(0, __float_as_int(x), 0x143, 0xf, 0xf, true);
  x += __int_as_float(v);
  return x;
}

__device__ __forceinline__ float xsum(float x) {
  #pragma unroll
  for (int off = 32; off >= 1; off >>= 1) x += __shfl_xor(x, off, 64);
  return x;
}
__device__ __forceinline__ float xmax(float x) {
  #pragma unroll
  for (int off = 32; off >= 1; off >>= 1) x = fmaxf(x, __shfl_xor(x, off, 64));
  return x;
}

__global__ __launch_bounds__(256) void k_pre(const float* __restrict__ Wemb,
                                             const float* __restrict__ bemb,
                                             const float* __restrict__ Wqg,
                                             const float* __restrict__ Wrg,
                                             const float* __restrict__ vg,
                                             const float* __restrict__ Wqp,
                                             const float* __restrict__ Wrp,
                                             const float* __restrict__ vp,
                                             float* __restrict__ ws) {
  __shared__ float mg_s[2][128], mp_s[2][128], cg_s[128], cp_s[128];
  __shared__ float pg_s[2][128], pc_s[128];
  int t = threadIdx.x, blk = blockIdx.x;
  if (blk > 0) {
    int f = (blk - 1) * 256 + t;
    ws[WS_WQT + f] = Wqg[(f & 127) * Hd + (f >> 7)];
    return;
  }
  int j = t >> 7, hh = t & 127;
  float ag = 0.f, ap = 0.f;
  for (int k = 0; k < 128; ++k) {
    float we = Wemb[j * 128 + k];
    ag = fmaf(we, Wrg[k * 128 + hh], ag);
    ap = fmaf(we, Wrp[k * 128 + hh], ap);
  }
  mg_s[j][hh] = ag; mp_s[j][hh] = ap;
  if (t < 128) {
    float cgv = 0.f, cpv = 0.f;
    for (int k = 0; k < 128; ++k) {
      float be = bemb[k];
      cgv = fmaf(be, Wrg[k * 128 + t], cgv);
      cpv = fmaf(be, Wrp[k * 128 + t], cpv);
    }
    cg_s[t] = cgv; cp_s[t] = cpv;
  }
  __syncthreads();
  float pg = 0.f;
  for (int k = 0; k < 128; ++k) pg = fmaf(mg_s[j][k], Wqp[k * 128 + hh], pg);
  pg_s[j][hh] = pg;
  if (t < 128) {
    float pcv = 0.f;
    for (int k = 0; k < 128; ++k) pcv = fmaf(cg_s[k], Wqp[k * 128 + t], pcv);
    pc_s[t] = pcv + cp_s[t];
  }
  __syncthreads();
  if (t < 128) {
    float4* w4 = (float4*)ws;
    w4[WS_TG / 4 + t] = make_float4(mg_s[0][t], mg_s[1][t], vg[t], cg_s[t]);
    w4[WS_TP / 4 + t] = make_float4(mp_s[0][t], mp_s[1][t], vp[t], cp_s[t]);
    w4[WS_TQ / 4 + t] = make_float4(pg_s[0][t], pg_s[1][t], pc_s[t], 0.f);
    w4[WS_TW / 4 + t] = make_float4(Wemb[t], Wemb[128 + t], bemb[t], 0.f);
  }
}

__global__ __launch_bounds__(256) void k_init(const float* __restrict__ dinit,
                                              float* __restrict__ ws) {
  int i = blockIdx.x * 256 + threadIdx.x;
  if (i < BN) ws[WS_MASK + i] = 0.0f;
  if (i < BH) {
    ws[WS_H + i] = 0.0f;
    ws[WS_C + i] = 0.0f;
    ws[WS_DEC + i] = dinit[i & 127];
  }
}

// One step: gates GEMM + LSTM cell + rank-2 glimpse + rank-2 pointer + sample.
// 256 blocks x 1024 threads, 4 batch rows/block. All blocks in phase -> L2
// dedups the 512 KB weight stream per XCD.
__global__ __launch_bounds__(1024) void k_step(const float* __restrict__ ip,
                                               const float* __restrict__ Wi,
                                               const float* __restrict__ Wh,
                                               const float* __restrict__ bl,
                                               float* __restrict__ ws,
                                               float* __restrict__ out, int st) {
  __shared__ __align__(16) float gpart[8][4][G4];   // 64 KB
  __shared__ __align__(16) float h_s[4][Hd];
  __shared__ __align__(16) float c_s[4][Hd];
  __shared__ __align__(16) float dec_s[4][Hd];
  __shared__ __align__(16) float qbuf[4][Hd];
  __shared__ __align__(16) float u_s[4][64];
  __shared__ __align__(16) float ip_s[4][Npt * 2];
  __shared__ __align__(16) float mask_s[4][Npt];

  int t = threadIdx.x, blk = blockIdx.x;
  int w = t >> 6, lane = t & 63;
  const float4* ws4 = (const float4*)ws;
  float* hg = ws + WS_H;
  float* cg = ws + WS_C;
  float* dg = ws + WS_DEC;
  float* mg = ws + WS_MASK;

  // ---- stage state ----
  if (t < 512) {
    int r = t >> 7, hh = t & 127;
    size_t gi = (size_t)(blk * 4 + r) * Hd + hh;
    h_s[r][hh] = hg[gi];
    c_s[r][hh] = cg[gi];
    dec_s[r][hh] = dg[gi];
  }
  if (t < 200) {
    ((float2*)ip_s)[t] = ((const float2*)ip)[blk * 200 + t];
    ((float*)mask_s)[t] = mg[(size_t)blk * 200 + t];
  }
  __syncthreads();

  // ---- A1: gates partials: 8 k-chunks x 128 j-tiles(4 cols) x 4 rows ----
  {
    int kh = t >> 7, jt = t & 127;
    int k0 = kh * 16;
    float acc[4][4];
    #pragma unroll
    for (int r = 0; r < 4; ++r)
      #pragma unroll
      for (int c = 0; c < 4; ++c) acc[r][c] = 0.f;
    #pragma unroll
    for (int k4 = 0; k4 < 16; k4 += 4) {
      float xr[4][4], hr[4][4];
      #pragma unroll
      for (int r = 0; r < 4; ++r) {
        *(float4*)&xr[r][0] = *(const float4*)&dec_s[r][k0 + k4];
        *(float4*)&hr[r][0] = *(const float4*)&h_s[r][k0 + k4];
      }
      #pragma unroll
      for (int kk = 0; kk < 4; ++kk) {
        float wi4[4], wh4[4];
        *(float4*)wi4 = *(const float4*)&Wi[(k0 + k4 + kk) * G4 + jt * 4];
        *(float4*)wh4 = *(const float4*)&Wh[(k0 + k4 + kk) * G4 + jt * 4];
        #pragma unroll
        for (int r = 0; r < 4; ++r)
          #pragma unroll
          for (int c = 0; c < 4; ++c)
            acc[r][c] = fmaf(xr[r][kk], wi4[c], fmaf(hr[r][kk], wh4[c], acc[r][c]));
      }
    }
    #pragma unroll
    for (int r = 0; r < 4; ++r)
      *(float4*)&gpart[kh][r][jt * 4] = *(float4*)&acc[r][0];
  }
  __syncthreads();
  // ---- A2: combine + bias + LSTM cell ----
  if (t < 512) {
    int r = t >> 7, hh = t & 127;
    float gi = bl[hh], gf = bl[128 + hh], gg = bl[256 + hh], go = bl[384 + hh];
    #pragma unroll
    for (int kh = 0; kh < 8; ++kh) {
      gi += gpart[kh][r][hh];
      gf += gpart[kh][r][128 + hh];
      gg += gpart[kh][r][256 + hh];
      go += gpart[kh][r][384 + hh];
    }
    float c2 = fsig(gf) * c_s[r][hh] + fsig(gi) * ftanh(gg);
    float h2 = fsig(go) * ftanh(c2);
    size_t gix = (size_t)(blk * 4 + r) * Hd + hh;
    cg[gix] = c2;
    hg[gix] = h2;
    h_s[r][hh] = h2;
  }
  __syncthreads();
  // ---- B: q = h2 @ Wqg + cg ----
  if (t < 512) {
    int r = t >> 7, hh = t & 127;
    float a = 0.f;
    const float* wrow = ws + WS_WQT + hh * 128;
    #pragma unroll
    for (int k = 0; k < 128; k += 4) {
      float wv[4], hv[4];
      *(float4*)wv = *(const float4*)&wrow[k];
      *(float4*)hv = *(const float4*)&h_s[r][k];
      a = fmaf(hv[0], wv[0], fmaf(hv[1], wv[1], fmaf(hv[2], wv[2], fmaf(hv[3], wv[3], a))));
    }
    qbuf[r][hh] = a + ws4[WS_TG / 4 + hh].w;
  }
  __syncthreads();
  int cr = w & 3, ni = w >> 2;
  int nIter = (ni == 3) ? 11 : 13;
  // ---- C: glimpse scores ----
  {
    float4 tA = ws4[WS_TG / 4 + lane];
    float4 tB = ws4[WS_TG / 4 + 64 + lane];
    float q0 = qbuf[cr][lane], q1 = qbuf[cr][64 + lane];
    for (int i = 0; i < nIter; ++i) {
      int n = ni * 13 + i;
      float2 pn = ((float2*)ip_s)[cr * Npt + n];
      float a0 = fmaf(pn.x, tA.x, fmaf(pn.y, tA.y, q0));
      float a1 = fmaf(pn.x, tB.x, fmaf(pn.y, tB.y, q1));
      float s = tA.z * ftanh(a0) + tB.z * ftanh(a1);
      s = dpp_sum64(s);
      if (lane == 63) u_s[cr][n] = s;
    }
  }
  __syncthreads();
  // ---- D: glimpse softmax -> (s0,s1) -> rank-2 pointer query ----
  if (w < 4) {
    int r = w;
    float2 ipn = make_float2(0.f, 0.f);
    float x = -INFINITY;
    if (lane < Npt) {
      ipn = ((float2*)ip_s)[r * Npt + lane];
      x = u_s[r][lane] - NEGC * mask_s[r][lane];
    }
    float m = xmax(x);
    float e = (lane < Npt) ? __expf(x - m) : 0.f;
    float ssum = xsum(e);
    float p = e / ssum;
    float s0 = xsum(p * ipn.x);
    float s1 = xsum(p * ipn.y);
    float4 tq0 = ws4[WS_TQ / 4 + lane];
    float4 tq1 = ws4[WS_TQ / 4 + 64 + lane];
    qbuf[r][lane]      = fmaf(s0, tq0.x, fmaf(s1, tq0.y, tq0.z));
    qbuf[r][64 + lane] = fmaf(s0, tq1.x, fmaf(s1, tq1.y, tq1.z));
  }
  __syncthreads();
  // ---- E: pointer scores ----
  {
    float4 tA = ws4[WS_TP / 4 + lane];
    float4 tB = ws4[WS_TP / 4 + 64 + lane];
    float q0 = qbuf[cr][lane], q1 = qbuf[cr][64 + lane];
    for (int i = 0; i < nIter; ++i) {
      int n = ni * 13 + i;
      float2 pn = ((float2*)ip_s)[cr * Npt + n];
      float a0 = fmaf(pn.x, tA.x, fmaf(pn.y, tA.y, q0));
      float a1 = fmaf(pn.x, tB.x, fmaf(pn.y, tB.y, q1));
      float s = tA.z * ftanh(a0) + tB.z * ftanh(a1);
      s = dpp_sum64(s);
      if (lane == 63) u_s[cr][n] = CTANH * ftanh(s);
    }
  }
  __syncthreads();
  // ---- F: pointer softmax / argmax / outputs / mask / dec_next ----
  if (w < 4) {
    int r = w, b = blk * 4 + r;
    float2 ipn = make_float2(0.f, 0.f);
    float x = -INFINITY;
    if (lane < Npt) {
      ipn = ((float2*)ip_s)[r * Npt + lane];
      x = u_s[r][lane] - NEGC * mask_s[r][lane];
    }
    float m = xmax(x);
    float sh = x - m;
    float e = (lane < Npt) ? __expf(sh) : 0.f;
    float ssum = xsum(e);
    float ls = __logf(ssum);
    float prob = e / ssum;
    if (lane < Npt) {
      out[OFF_LP + ((size_t)b * Tt + st) * Npt + lane] = sh - ls;
      out[OFF_P + ((size_t)b * Tt + st) * Npt + lane] = prob;
    }
    float pv = (lane < Npt) ? prob : -1.f;
    int idx = lane;
    #pragma unroll
    for (int off = 32; off >= 1; off >>= 1) {
      float po = __shfl_xor(pv, off, 64);
      int io = __shfl_xor(idx, off, 64);
      if (po > pv || (po == pv && io < idx)) { pv = po; idx = io; }
    }
    int a = idx;
    float p0a = __shfl(ipn.x, a, 64);
    float p1a = __shfl(ipn.y, a, 64);
    if (lane == 0) {
      out[OFF_A + (size_t)b * Tt + st] = (float)a;
      out[OFF_C + ((size_t)b * Tt + st) * 2 + 0] = p0a;
      out[OFF_C + ((size_t)b * Tt + st) * 2 + 1] = p1a;
      mg[(size_t)b * Npt + a] = 1.0f;
    }
    float4 tw0 = ws4[WS_TW / 4 + lane];
    float4 tw1 = ws4[WS_TW / 4 + 64 + lane];
    dg[(size_t)b * Hd + lane]      = fmaf(p0a, tw0.x, fmaf(p1a, tw0.y, tw0.z));
    dg[(size_t)b * Hd + lane + 64] = fmaf(p0a, tw1.x, fmaf(p1a, tw1.y, tw1.z));
  }
}

__global__ __launch_bounds__(256) void k_mm128(const float* __restrict__ A,
                                               const float* __restrict__ W,
                                               const float* __restrict__ bias,
                                               float* __restrict__ C, int relu) {
  __shared__ __align__(16) float As[8][128];
  int t = threadIdx.x;
  int r0 = blockIdx.x * 8;
  ((float4*)As)[t] = ((const float4*)(A + (size_t)r0 * Hd))[t];
  __syncthreads();
  int hh = t & 127, rg = t >> 7;
  float acc[4] = {0.f, 0.f, 0.f, 0.f};
  for (int k = 0; k < 128; k += 4) {
    float w0 = W[(k + 0) * Hd + hh], w1 = W[(k + 1) * Hd + hh];
    float w2 = W[(k + 2) * Hd + hh], w3 = W[(k + 3) * Hd + hh];
    #pragma unroll
    for (int i = 0; i < 4; ++i) {
      float4 av = *(const float4*)&As[rg * 4 + i][k];
      acc[i] += av.x * w0 + av.y * w1 + av.z * w2 + av.w * w3;
    }
  }
  float bv = bias ? bias[hh] : 0.f;
  #pragma unroll
  for (int i = 0; i < 4; ++i) {
    float o = acc[i] + bv;
    if (relu) o = fmaxf(o, 0.f);
    C[(size_t)(r0 + rg * 4 + i) * Hd + hh] = o;
  }
}

__global__ __launch_bounds__(256) void k_final(const float* __restrict__ t2,
                                               const float* __restrict__ W2,
                                               const float* __restrict__ b2,
                                               float* out) {
  int w = threadIdx.x >> 6, lane = threadIdx.x & 63;
  int b = blockIdx.x * 4 + w;
  float s = t2[(size_t)b * Hd + lane] * W2[lane] + t2[(size_t)b * Hd + lane + 64] * W2[lane + 64];
  s = xsum(s);
  if (lane == 0) out[OFF_V + b] = s + b2[0];

  const float* cbp = out + OFF_C + (size_t)b * Tt * 2;
  float r = 0.f;
  if (lane < Tt - 1) {
    float dx = cbp[(lane + 1) * 2] - cbp[lane * 2];
    float dy = cbp[(lane + 1) * 2 + 1] - cbp[lane * 2 + 1];
    r = sqrtf(dx * dx + dy * dy + 1e-10f);
  } else if (lane == Tt - 1) {
    float dx = cbp[0] - cbp[(Tt - 1) * 2];
    float dy = cbp[1] - cbp[(Tt - 1) * 2 + 1];
    r = sqrtf(dx * dx + dy * dy + 1e-10f);
  }
  r = xsum(r);
  if (lane == 0) out[OFF_R + b] = r;
}

extern "C" void kernel_launch(void* const* d_in, const int* in_sizes, int n_in,
                              void* d_out, int out_size, void* d_ws, size_t ws_size,
                              hipStream_t stream) {
  (void)in_sizes; (void)n_in; (void)out_size; (void)ws_size;
  const float* ip    = (const float*)d_in[0];
  const float* Wemb  = (const float*)d_in[1];
  const float* bemb  = (const float*)d_in[2];
  const float* dinit = (const float*)d_in[3];
  const float* Wi    = (const float*)d_in[4];
  const float* Wh    = (const float*)d_in[5];
  const float* bl    = (const float*)d_in[6];
  const float* Wqg   = (const float*)d_in[7];
  const float* Wrg   = (const float*)d_in[8];
  const float* vg    = (const float*)d_in[9];
  const float* Wqp   = (const float*)d_in[10];
  const float* Wrp   = (const float*)d_in[11];
  const float* vp    = (const float*)d_in[12];
  // d_in[13..16], d_in[18] dead: critic N=1 softmax == 1 => hy = e_c
  const float* Wrc   = (const float*)d_in[17];
  const float* W1    = (const float*)d_in[19];
  const float* b1    = (const float*)d_in[20];
  const float* W2    = (const float*)d_in[21];
  const float* b2    = (const float*)d_in[22];
  float* out = (float*)d_out;
  float* ws  = (float*)d_ws;

  k_pre<<<65, 256, 0, stream>>>(Wemb, bemb, Wqg, Wrg, vg, Wqp, Wrp, vp, ws);
  k_init<<<512, 256, 0, stream>>>(dinit, ws);
  for (int st = 0; st < Tt; ++st) {
    k_step<<<256, 1024, 0, stream>>>(ip, Wi, Wh, bl, ws, out, st);
  }
  k_mm128<<<128, 256, 0, stream>>>(ws + WS_DEC, Wrc, nullptr, ws + WS_EC, 0);
  k_mm128<<<128, 256, 0, stream>>>(ws + WS_EC, W1, b1, ws + WS_T2, 1);
  k_final<<<256, 256, 0, stream>>>(ws + WS_T2, W2, b2, out);
}